// Round 4
// baseline (674.766 us; speedup 1.0000x reference)
//
#include <hip/hip_runtime.h>
#include <hip/hip_cooperative_groups.h>
#include <math.h>

namespace cg = cooperative_groups;

#define DIM     2048
#define NEXP    64
#define CAP     128
#define NTOK    8192
#define NTILE   256            // 256 tiles of 32 tokens = 256 blocks (1/CU)
#define KC      256            // K-chunk staged in LDS
#define NCH     (DIM/KC)       // 8 chunks
#define XWSTR   260            // row stride for xs/ws tiles (KC+4)
#define PSTR    68             // row stride for partial/logit tiles
#define RF      67108864       // floats per output region (S*E*C)

typedef float vfloat4 __attribute__((ext_vector_type(4)));

// ============================================================
// Single cooperative kernel: fill+GEMM+softmax/rank -> grid.sync ->
// prefix/l_aux (block 0) -> grid.sync -> per-block scatter from LDS.
// Per-token results (expert, gate, rank) never leave LDS.
// ============================================================
__global__ __launch_bounds__(512, 2) void moe_all(
    const float* __restrict__ x, const float* __restrict__ wg,
    float* __restrict__ out,
    float* __restrict__ me_partial, int* __restrict__ counts,
    int* __restrict__ bo_g)
{
    __shared__ __align__(16) float smem[(32 + NEXP) * XWSTR]; // 99,840 B
    __shared__ float me_w[8 * NEXP];
    __shared__ int   cnt_w[8 * NEXP];
    __shared__ int   exp_s[32];
    __shared__ int   rk_s[32];
    __shared__ float gt_s[32];
    __shared__ float laux_s;
    // phase-B scratch (block 0 only)
    __shared__ int   cnt_l[8 * NEXP];
    __shared__ float me_l[8 * NEXP];
    __shared__ int   cnt_tot[NEXP];
    __shared__ float me_tot[NEXP];

    float* xs = smem;                 // [32][XWSTR]
    float* ws = smem + 32 * XWSTR;    // [64][XWSTR]

    const int tid  = threadIdx.x;
    const int gb   = blockIdx.x;
    const int tok0 = gb * 32;
    const int sl   = tid >> 5;        // k-slice 0..15
    const int i    = tid & 31;
    const int tg   = i & 3;           // token group
    const int eg   = i >> 2;          // expert group 0..7
    const int kb   = sl * 16;         // slice's kk base within chunk

    vfloat4* o4 = reinterpret_cast<vfloat4*>(out);
    const vfloat4 z4 = {0.f, 0.f, 0.f, 0.f};
    if (gb == 0 && tid == 0)
        out[134217728ull] = 0.0f;     // out[2*RF], past the f4 span

    float acc[8][8] = {};

    // ---------------- phase A: fill + GEMM (R0's proven structure) -------
    for (int ch = 0; ch < NCH; ++ch) {
        const int k0 = ch * KC;
        #pragma unroll
        for (int q = 0; q < 4; ++q) {
            int id = tid + (q << 9);
            int r = id >> 6, c = id & 63;
            float4 v = *(const float4*)(x + (size_t)(tok0 + r) * DIM + k0 + 4 * c);
            *(float4*)(&xs[r * XWSTR + 4 * c]) = v;
        }
        #pragma unroll
        for (int q = 0; q < 8; ++q) {
            int id = tid + (q << 9);
            int r = id >> 6, c = id & 63;
            float4 v = *(const float4*)(wg + (size_t)r * DIM + k0 + 4 * c);
            *(float4*)(&ws[r * XWSTR + 4 * c]) = v;
        }
        // this chunk's slice of the 512 MiB zero-fill (NT: keep L2 for wg/x)
        {
            size_t base = (size_t)gb * 131072 + (size_t)(ch << 14) + tid;
            #pragma unroll
            for (int q = 0; q < 32; ++q)
                __builtin_nontemporal_store(z4, &o4[base + (size_t)(q << 9)]);
        }
        __syncthreads();

        #pragma unroll
        for (int q2 = 0; q2 < 4; ++q2) {
            const int kk = kb + 4 * q2;
            float4 xt[8], we[8];
            #pragma unroll
            for (int j = 0; j < 8; ++j)
                xt[j] = *(const float4*)(&xs[(tg + 4 * j) * XWSTR + kk]);
            #pragma unroll
            for (int m = 0; m < 8; ++m)
                we[m] = *(const float4*)(&ws[(eg + 8 * m) * XWSTR + kk]);
            #pragma unroll
            for (int j = 0; j < 8; ++j)
                #pragma unroll
                for (int m = 0; m < 8; ++m) {
                    acc[j][m] = fmaf(xt[j].x, we[m].x, acc[j][m]);
                    acc[j][m] = fmaf(xt[j].y, we[m].y, acc[j][m]);
                    acc[j][m] = fmaf(xt[j].z, we[m].z, acc[j][m]);
                    acc[j][m] = fmaf(xt[j].w, we[m].w, acc[j][m]);
                }
        }
        __syncthreads();
    }

    // ---- reduce 16 k-slices through LDS ----
    float* part = smem;                 // [8][32][PSTR]
    float* lgt  = smem + 8 * 32 * PSTR; // [32][PSTR]
    if (sl >= 8) {
        #pragma unroll
        for (int j = 0; j < 8; ++j)
            #pragma unroll
            for (int m = 0; m < 8; ++m)
                part[((sl - 8) * 32 + tg + 4 * j) * PSTR + eg + 8 * m] = acc[j][m];
    }
    __syncthreads();
    if (sl < 8) {
        #pragma unroll
        for (int j = 0; j < 8; ++j)
            #pragma unroll
            for (int m = 0; m < 8; ++m) {
                int idx = (sl * 32 + tg + 4 * j) * PSTR + eg + 8 * m;
                part[idx] += acc[j][m];
            }
    }
    __syncthreads();

    {
        int t  = tid >> 4;
        int e0 = (tid & 15) << 2;
        float4 a = {0, 0, 0, 0};
        #pragma unroll
        for (int s2 = 0; s2 < 8; ++s2) {
            float4 p = *(const float4*)(&part[(s2 * 32 + t) * PSTR + e0]);
            a.x += p.x; a.y += p.y; a.z += p.z; a.w += p.w;
        }
        *(float4*)(&lgt[t * PSTR + e0]) = a;
    }
    __syncthreads();

    // ---- softmax + argmax: 8 waves x 4 rows, lane = expert ----
    const int lane = tid & 63;
    const int wv   = tid >> 6;
    float me_acc  = 0.0f;
    int   cnt_acc = 0;
    #pragma unroll
    for (int r4 = 0; r4 < 4; ++r4) {
        int row = wv * 4 + r4;
        float v = lgt[row * PSTR + lane];
        float m = v; int mi = lane;
        #pragma unroll
        for (int off = 32; off > 0; off >>= 1) {
            float om  = __shfl_xor(m, off);
            int   omi = __shfl_xor(mi, off);
            if (om > m || (om == m && omi < mi)) { m = om; mi = omi; }
        }
        float ex = __expf(v - m);
        float sm = ex;
        #pragma unroll
        for (int off = 32; off > 0; off >>= 1) sm += __shfl_xor(sm, off);
        me_acc += ex / sm;
        if (lane == mi) {                 // per-token results stay in LDS
            exp_s[row] = mi;
            gt_s[row]  = 1.0f / sm;
            ++cnt_acc;
        }
    }
    me_w[wv * NEXP + lane]  = me_acc;
    cnt_w[wv * NEXP + lane] = cnt_acc;
    __syncthreads();

    if (tid < 32) {   // within-tile rank (token order)
        int e = exp_s[tid];
        int rk = 0;
        for (int u = 0; u < tid; ++u) rk += (exp_s[u] == e) ? 1 : 0;
        rk_s[tid] = rk;
    }
    if (tid < NEXP) {
        float ms = 0.f; int cs = 0;
        #pragma unroll
        for (int w = 0; w < 8; ++w) { ms += me_w[w * NEXP + tid]; cs += cnt_w[w * NEXP + tid]; }
        me_partial[gb * NEXP + tid] = ms;
        counts[gb * NEXP + tid]     = cs;
    }

    cg::grid_group grid = cg::this_grid();
    grid.sync();

    // ---------------- phase B: prefix + l_aux (block 0, 512 thr) --------
    if (gb == 0) {
        const int e = tid & 63;
        const int g = tid >> 6;          // 0..7, each handles 32 tiles
        int cs = 0; float ms = 0.f;
        #pragma unroll 4
        for (int t = g * 32; t < g * 32 + 32; ++t) {
            cs += counts[t * NEXP + e];
            ms += me_partial[t * NEXP + e];
        }
        cnt_l[g * NEXP + e] = cs;
        me_l[g * NEXP + e]  = ms;
        __syncthreads();
        if (g == 0) {
            int run = 0; float mt = 0.f;
            #pragma unroll
            for (int q = 0; q < 8; ++q) {
                int c = cnt_l[q * NEXP + e];
                cnt_l[q * NEXP + e] = run;
                run += c;
                mt  += me_l[q * NEXP + e];
            }
            cnt_tot[e] = run;
            me_tot[e]  = mt;
        }
        __syncthreads();
        int run = cnt_l[g * NEXP + e];
        #pragma unroll 4
        for (int t = g * 32; t < g * 32 + 32; ++t) {
            bo_g[t * NEXP + e] = run;
            run += counts[t * NEXP + e];
        }
        if (tid < NEXP) {
            float v = (me_tot[e] / (float)NTOK) * ((float)cnt_tot[e] / (float)NTOK);
            #pragma unroll
            for (int off = 32; off > 0; off >>= 1) v += __shfl_xor(v, off);
            if (e == 0) laux_s = v * (float)NEXP;
        }
    }
    __threadfence();
    grid.sync();

    // ---------------- phase C: per-block scatter from LDS ---------------
    if (tid < 32) {
        int e   = exp_s[tid];
        int loc = bo_g[gb * NEXP + e] + rk_s[tid];
        if (loc < CAP) {
            int p = 1 + (tok0 + tid) * (NEXP * CAP) + e * CAP + loc;
            out[(size_t)p]      = gt_s[tid];   // combine
            out[(size_t)p + RF] = 1.0f;        // dispatch
        }
    }
    if (gb == 0 && tid == 32) out[0] = laux_s; // l_aux
}

// ============================================================
// Fallback pair (R0's best-measured 2-launch config) used only if
// cooperative launch is rejected under graph capture.
// ============================================================
__global__ __launch_bounds__(512, 2) void gate_fill_fb(
    const float* __restrict__ x, const float* __restrict__ wg,
    float* __restrict__ out,
    int* __restrict__ expert_idx, float* __restrict__ gate_top,
    int* __restrict__ rank,
    float* __restrict__ me_partial, int* __restrict__ counts)
{
    __shared__ __align__(16) float smem[(32 + NEXP) * XWSTR];
    __shared__ float me_w[8 * NEXP];
    __shared__ int   cnt_w[8 * NEXP];
    __shared__ int   exp_s[32];

    float* xs = smem;
    float* ws = smem + 32 * XWSTR;

    const int tid  = threadIdx.x;
    const int gb   = blockIdx.x;
    const int tok0 = gb * 32;
    const int sl   = tid >> 5;
    const int i    = tid & 31;
    const int tg   = i & 3;
    const int eg   = i >> 2;
    const int kb   = sl * 16;

    vfloat4* o4 = reinterpret_cast<vfloat4*>(out);
    const vfloat4 z4 = {0.f, 0.f, 0.f, 0.f};
    if (gb == 0 && tid == 0) out[134217728ull] = 0.0f;

    float acc[8][8] = {};
    for (int ch = 0; ch < NCH; ++ch) {
        const int k0 = ch * KC;
        #pragma unroll
        for (int q = 0; q < 4; ++q) {
            int id = tid + (q << 9);
            int r = id >> 6, c = id & 63;
            float4 v = *(const float4*)(x + (size_t)(tok0 + r) * DIM + k0 + 4 * c);
            *(float4*)(&xs[r * XWSTR + 4 * c]) = v;
        }
        #pragma unroll
        for (int q = 0; q < 8; ++q) {
            int id = tid + (q << 9);
            int r = id >> 6, c = id & 63;
            float4 v = *(const float4*)(wg + (size_t)r * DIM + k0 + 4 * c);
            *(float4*)(&ws[r * XWSTR + 4 * c]) = v;
        }
        {
            size_t base = (size_t)gb * 131072 + (size_t)(ch << 14) + tid;
            #pragma unroll
            for (int q = 0; q < 32; ++q)
                __builtin_nontemporal_store(z4, &o4[base + (size_t)(q << 9)]);
        }
        __syncthreads();
        #pragma unroll
        for (int q2 = 0; q2 < 4; ++q2) {
            const int kk = kb + 4 * q2;
            float4 xt[8], we[8];
            #pragma unroll
            for (int j = 0; j < 8; ++j)
                xt[j] = *(const float4*)(&xs[(tg + 4 * j) * XWSTR + kk]);
            #pragma unroll
            for (int m = 0; m < 8; ++m)
                we[m] = *(const float4*)(&ws[(eg + 8 * m) * XWSTR + kk]);
            #pragma unroll
            for (int j = 0; j < 8; ++j)
                #pragma unroll
                for (int m = 0; m < 8; ++m) {
                    acc[j][m] = fmaf(xt[j].x, we[m].x, acc[j][m]);
                    acc[j][m] = fmaf(xt[j].y, we[m].y, acc[j][m]);
                    acc[j][m] = fmaf(xt[j].z, we[m].z, acc[j][m]);
                    acc[j][m] = fmaf(xt[j].w, we[m].w, acc[j][m]);
                }
        }
        __syncthreads();
    }

    float* part = smem;
    float* lgt  = smem + 8 * 32 * PSTR;
    if (sl >= 8) {
        #pragma unroll
        for (int j = 0; j < 8; ++j)
            #pragma unroll
            for (int m = 0; m < 8; ++m)
                part[((sl - 8) * 32 + tg + 4 * j) * PSTR + eg + 8 * m] = acc[j][m];
    }
    __syncthreads();
    if (sl < 8) {
        #pragma unroll
        for (int j = 0; j < 8; ++j)
            #pragma unroll
            for (int m = 0; m < 8; ++m)
                part[(sl * 32 + tg + 4 * j) * PSTR + eg + 8 * m] += acc[j][m];
    }
    __syncthreads();
    {
        int t  = tid >> 4;
        int e0 = (tid & 15) << 2;
        float4 a = {0, 0, 0, 0};
        #pragma unroll
        for (int s2 = 0; s2 < 8; ++s2) {
            float4 p = *(const float4*)(&part[(s2 * 32 + t) * PSTR + e0]);
            a.x += p.x; a.y += p.y; a.z += p.z; a.w += p.w;
        }
        *(float4*)(&lgt[t * PSTR + e0]) = a;
    }
    __syncthreads();

    const int lane = tid & 63;
    const int wv   = tid >> 6;
    float me_acc  = 0.0f;
    int   cnt_acc = 0;
    #pragma unroll
    for (int r4 = 0; r4 < 4; ++r4) {
        int row = wv * 4 + r4;
        float v = lgt[row * PSTR + lane];
        float m = v; int mi = lane;
        #pragma unroll
        for (int off = 32; off > 0; off >>= 1) {
            float om  = __shfl_xor(m, off);
            int   omi = __shfl_xor(mi, off);
            if (om > m || (om == m && omi < mi)) { m = om; mi = omi; }
        }
        float ex = __expf(v - m);
        float sm = ex;
        #pragma unroll
        for (int off = 32; off > 0; off >>= 1) sm += __shfl_xor(sm, off);
        me_acc += ex / sm;
        if (lane == mi) {
            expert_idx[tok0 + row] = mi;
            gate_top[tok0 + row]   = 1.0f / sm;
            exp_s[row] = mi;
            ++cnt_acc;
        }
    }
    me_w[wv * NEXP + lane]  = me_acc;
    cnt_w[wv * NEXP + lane] = cnt_acc;
    __syncthreads();

    if (tid < 32) {
        int e = exp_s[tid];
        int rk = 0;
        for (int u = 0; u < tid; ++u) rk += (exp_s[u] == e) ? 1 : 0;
        rank[tok0 + tid] = rk;
    }
    if (tid < NEXP) {
        float ms = 0.f; int cs = 0;
        #pragma unroll
        for (int w = 0; w < 8; ++w) { ms += me_w[w * NEXP + tid]; cs += cnt_w[w * NEXP + tid]; }
        me_partial[gb * NEXP + tid] = ms;
        counts[gb * NEXP + tid]     = cs;
    }
}

__global__ __launch_bounds__(1024) void prefix_laux_fb(
    const float* __restrict__ me_partial, const int* __restrict__ counts,
    const int* __restrict__ expert_idx, const int* __restrict__ rank,
    const float* __restrict__ gate_top, float* __restrict__ out)
{
    __shared__ int   bo_l[NTILE * NEXP];
    __shared__ int   cnt_l[16 * NEXP];
    __shared__ float me_l[16 * NEXP];
    __shared__ int   cnt_tot[NEXP];
    __shared__ float me_tot[NEXP];

    const int tid = threadIdx.x;
    const int e   = tid & 63;
    const int g   = tid >> 6;

    int cs = 0; float ms = 0.f;
    #pragma unroll
    for (int q = 0; q < 16; ++q) {
        int t = g * 16 + q;
        cs += counts[t * NEXP + e];
        ms += me_partial[t * NEXP + e];
    }
    cnt_l[g * NEXP + e] = cs;
    me_l[g * NEXP + e]  = ms;
    __syncthreads();

    if (g == 0) {
        int run = 0; float mt = 0.f;
        #pragma unroll
        for (int q = 0; q < 16; ++q) {
            int c = cnt_l[q * NEXP + e];
            cnt_l[q * NEXP + e] = run;
            run += c;
            mt  += me_l[q * NEXP + e];
        }
        cnt_tot[e] = run;
        me_tot[e]  = mt;
    }
    __syncthreads();

    int run = cnt_l[g * NEXP + e];
    #pragma unroll
    for (int q = 0; q < 16; ++q) {
        int t = g * 16 + q;
        bo_l[t * NEXP + e] = run;
        run += counts[t * NEXP + e];
    }
    __syncthreads();

    if (tid < NEXP) {
        float v = (me_tot[e] / (float)NTOK) * ((float)cnt_tot[e] / (float)NTOK);
        #pragma unroll
        for (int off = 32; off > 0; off >>= 1) v += __shfl_xor(v, off);
        if (e == 0) out[0] = v * (float)NEXP;
    }

    #pragma unroll
    for (int ii = 0; ii < 8; ++ii) {
        int s  = tid + (ii << 10);
        int ex = expert_idx[s];
        int loc = bo_l[(s >> 5) * NEXP + ex] + rank[s];
        if (loc < CAP) {
            size_t off = 1 + (size_t)s * (NEXP * CAP) + (size_t)ex * CAP + loc;
            out[off]              = gate_top[s];
            out[off + (size_t)RF] = 1.0f;
        }
    }
}

extern "C" void kernel_launch(void* const* d_in, const int* in_sizes, int n_in,
                              void* d_out, int out_size, void* d_ws, size_t ws_size,
                              hipStream_t stream)
{
    const float* x  = (const float*)d_in[0];
    const float* wg = (const float*)d_in[1];
    float* out = (float*)d_out;

    char* ws = (char*)d_ws;
    float* me_partial = (float*)(ws);             // 64 KB
    int*   counts     = (int*)  (ws + 65536);     // 64 KB
    int*   bo_g       = (int*)  (ws + 131072);    // 64 KB
    int*   expert_idx = (int*)  (ws + 196608);    // 32 KB (fallback only)
    float* gate_top   = (float*)(ws + 229376);    // 32 KB (fallback only)
    int*   rank       = (int*)  (ws + 262144);    // 32 KB (fallback only)

    void* args[] = { (void*)&x, (void*)&wg, (void*)&out,
                     (void*)&me_partial, (void*)&counts, (void*)&bo_g };
    hipError_t err = hipLaunchCooperativeKernel(
        (const void*)moe_all, dim3(NTILE), dim3(512), args, 0, stream);
    if (err != hipSuccess) {
        // cooperative launch rejected (e.g. under capture): R0 fallback
        gate_fill_fb<<<NTILE, 512, 0, stream>>>(x, wg, out, expert_idx,
                                                gate_top, rank, me_partial,
                                                counts);
        prefix_laux_fb<<<1, 1024, 0, stream>>>(me_partial, counts, expert_idx,
                                               rank, gate_top, out);
    }
}

// Round 5
// 608.244 us; speedup vs baseline: 1.1094x; 1.1094x over previous
//
#include <hip/hip_runtime.h>
#include <math.h>

#define DIM     2048
#define NEXP    64
#define CAP     128
#define NTOK    8192
#define NTILE   256            // 256 tiles of 32 tokens = 256 blocks = 1/CU
#define KC      256            // K-chunk staged in LDS
#define NCH     (DIM/KC)       // 8 chunks
#define XWSTR   260            // row stride for xs/ws tiles (KC+4)
#define PSTR    68             // row stride for partial/logit tiles
#define RF      67108864       // floats per output region (S*E*C)

typedef float vfloat4 __attribute__((ext_vector_type(4)));

// ============================================================
// Single worker kernel. Phase A = R0's proven fill+GEMM+softmax+rank
// (594.5 us config), with per-token results kept in LDS. Then a
// decoupled-lookback prefix replaces the separate prefix_laux kernel:
//   publish(counts,me) -> release flag -> wait ALL flags ->
//   distributed lookback (<=32 loads/lane) -> scatter from LDS.
// publish-before-wait => acyclic dependency => deadlock-free; 103 KB LDS
// forces 1 block/CU so all 256 blocks are co-resident. The all-flags wait
// also sequences each block's scatter after EVERY block's zero-fill
// (flags are set after a __threadfence that writes the fill back to the
// coherent point), which is required because scatter targets live in
// other blocks' fill ranges.
// ============================================================
__global__ __launch_bounds__(512, 2) void moe_one(
    const float* __restrict__ x, const float* __restrict__ wg,
    float* __restrict__ out,
    int* __restrict__ counts_g, float* __restrict__ me_g,
    int* __restrict__ flags)
{
    __shared__ __align__(16) float smem[(32 + NEXP) * XWSTR]; // 99,840 B
    __shared__ float me_w[8 * NEXP];
    __shared__ int   cnt_w[8 * NEXP];
    __shared__ int   exp_s[32];
    __shared__ int   rk_s[32];
    __shared__ float gt_s[32];
    __shared__ int   bo_s[NEXP];

    float* xs = smem;                 // [32][XWSTR]
    float* ws = smem + 32 * XWSTR;    // [64][XWSTR]

    const int tid  = threadIdx.x;
    const int gb   = blockIdx.x;
    const int tok0 = gb * 32;
    const int sl   = tid >> 5;        // k-slice 0..15
    const int i    = tid & 31;
    const int tg   = i & 3;           // token group
    const int eg   = i >> 2;          // expert group 0..7
    const int kb   = sl * 16;         // slice's kk base within chunk

    vfloat4* o4 = reinterpret_cast<vfloat4*>(out);
    const vfloat4 z4 = {0.f, 0.f, 0.f, 0.f};
    if (gb == 0 && tid == 0)
        out[134217728ull] = 0.0f;     // out[2*RF], past the f4 span

    float acc[8][8] = {};

    // ---------------- phase A: fill + GEMM (R0's proven structure) -------
    for (int ch = 0; ch < NCH; ++ch) {
        const int k0 = ch * KC;
        #pragma unroll
        for (int q = 0; q < 4; ++q) {
            int id = tid + (q << 9);
            int r = id >> 6, c = id & 63;
            float4 v = *(const float4*)(x + (size_t)(tok0 + r) * DIM + k0 + 4 * c);
            *(float4*)(&xs[r * XWSTR + 4 * c]) = v;
        }
        #pragma unroll
        for (int q = 0; q < 8; ++q) {
            int id = tid + (q << 9);
            int r = id >> 6, c = id & 63;
            float4 v = *(const float4*)(wg + (size_t)r * DIM + k0 + 4 * c);
            *(float4*)(&ws[r * XWSTR + 4 * c]) = v;
        }
        // this chunk's slice of the 512 MiB zero-fill
        {
            size_t base = (size_t)gb * 131072 + (size_t)(ch << 14) + tid;
            #pragma unroll
            for (int q = 0; q < 32; ++q)
                __builtin_nontemporal_store(z4, &o4[base + (size_t)(q << 9)]);
        }
        __syncthreads();

        #pragma unroll
        for (int q2 = 0; q2 < 4; ++q2) {
            const int kk = kb + 4 * q2;
            float4 xt[8], we[8];
            #pragma unroll
            for (int j = 0; j < 8; ++j)
                xt[j] = *(const float4*)(&xs[(tg + 4 * j) * XWSTR + kk]);
            #pragma unroll
            for (int m = 0; m < 8; ++m)
                we[m] = *(const float4*)(&ws[(eg + 8 * m) * XWSTR + kk]);
            #pragma unroll
            for (int j = 0; j < 8; ++j)
                #pragma unroll
                for (int m = 0; m < 8; ++m) {
                    acc[j][m] = fmaf(xt[j].x, we[m].x, acc[j][m]);
                    acc[j][m] = fmaf(xt[j].y, we[m].y, acc[j][m]);
                    acc[j][m] = fmaf(xt[j].z, we[m].z, acc[j][m]);
                    acc[j][m] = fmaf(xt[j].w, we[m].w, acc[j][m]);
                }
        }
        __syncthreads();
    }

    // ---- reduce 16 k-slices through LDS ----
    float* part = smem;                 // [8][32][PSTR]
    float* lgt  = smem + 8 * 32 * PSTR; // [32][PSTR]
    if (sl >= 8) {
        #pragma unroll
        for (int j = 0; j < 8; ++j)
            #pragma unroll
            for (int m = 0; m < 8; ++m)
                part[((sl - 8) * 32 + tg + 4 * j) * PSTR + eg + 8 * m] = acc[j][m];
    }
    __syncthreads();
    if (sl < 8) {
        #pragma unroll
        for (int j = 0; j < 8; ++j)
            #pragma unroll
            for (int m = 0; m < 8; ++m) {
                int idx = (sl * 32 + tg + 4 * j) * PSTR + eg + 8 * m;
                part[idx] += acc[j][m];
            }
    }
    __syncthreads();

    {
        int t  = tid >> 4;
        int e0 = (tid & 15) << 2;
        float4 a = {0, 0, 0, 0};
        #pragma unroll
        for (int s2 = 0; s2 < 8; ++s2) {
            float4 p = *(const float4*)(&part[(s2 * 32 + t) * PSTR + e0]);
            a.x += p.x; a.y += p.y; a.z += p.z; a.w += p.w;
        }
        *(float4*)(&lgt[t * PSTR + e0]) = a;
    }
    __syncthreads();

    // ---- softmax + argmax: 8 waves x 4 rows, lane = expert ----
    const int lane = tid & 63;
    const int wv   = tid >> 6;
    float me_acc  = 0.0f;
    int   cnt_acc = 0;
    #pragma unroll
    for (int r4 = 0; r4 < 4; ++r4) {
        int row = wv * 4 + r4;
        float v = lgt[row * PSTR + lane];
        float m = v; int mi = lane;
        #pragma unroll
        for (int off = 32; off > 0; off >>= 1) {
            float om  = __shfl_xor(m, off);
            int   omi = __shfl_xor(mi, off);
            if (om > m || (om == m && omi < mi)) { m = om; mi = omi; }
        }
        float ex = __expf(v - m);
        float sm = ex;
        #pragma unroll
        for (int off = 32; off > 0; off >>= 1) sm += __shfl_xor(sm, off);
        me_acc += ex / sm;
        if (lane == mi) {                 // per-token results stay in LDS
            exp_s[row] = mi;
            gt_s[row]  = 1.0f / sm;
            ++cnt_acc;
        }
    }
    me_w[wv * NEXP + lane]  = me_acc;
    cnt_w[wv * NEXP + lane] = cnt_acc;
    __syncthreads();

    if (tid < 32) {   // within-tile rank (token order)
        int e = exp_s[tid];
        int rk = 0;
        for (int u = 0; u < tid; ++u) rk += (exp_s[u] == e) ? 1 : 0;
        rk_s[tid] = rk;
    }
    if (tid < NEXP) {  // publish this tile's per-expert count + me partial
        float ms = 0.f; int cs = 0;
        #pragma unroll
        for (int w = 0; w < 8; ++w) { ms += me_w[w * NEXP + tid]; cs += cnt_w[w * NEXP + tid]; }
        counts_g[gb * NEXP + tid] = cs;
        me_g[gb * NEXP + tid]     = ms;
    }
    __syncthreads();   // per-wave vmcnt(0): publish stores retired in L2

    if (tid == 0) {
        __threadfence();   // write back this XCD's L2 to the coherent point
        __hip_atomic_store(&flags[gb], 1, __ATOMIC_RELEASE,
                           __HIP_MEMORY_SCOPE_AGENT);
    }
    // wait for ALL 256 flags (publish-before-wait => no deadlock)
    if (tid < NTILE) {
        while (__hip_atomic_load(&flags[tid], __ATOMIC_ACQUIRE,
                                 __HIP_MEMORY_SCOPE_AGENT) == 0)
            __builtin_amdgcn_s_sleep(2);
    }
    __syncthreads();

    // ---- distributed lookback: base[e] = sum_{t<gb} counts[t][e] --------
    // 8 waves x strided blocks, lane = expert; <=32 uncached loads/lane.
    {
        const int e = tid & 63;
        const int w = tid >> 6;
        const int lim = (gb == 0) ? NTILE : gb;   // block 0 computes totals
        int csum = 0; float msum = 0.f;
        for (int t = w; t < lim; t += 8) {
            csum += __hip_atomic_load(&counts_g[t * NEXP + e], __ATOMIC_RELAXED,
                                      __HIP_MEMORY_SCOPE_AGENT);
            if (gb == 0)
                msum += __hip_atomic_load(&me_g[t * NEXP + e], __ATOMIC_RELAXED,
                                          __HIP_MEMORY_SCOPE_AGENT);
        }
        cnt_w[w * NEXP + e] = csum;
        me_w[w * NEXP + e]  = msum;
    }
    __syncthreads();
    if (tid < NEXP) {
        int b = 0; float mt = 0.f;
        #pragma unroll
        for (int q = 0; q < 8; ++q) { b += cnt_w[q * NEXP + tid]; mt += me_w[q * NEXP + tid]; }
        bo_s[tid] = (gb == 0) ? 0 : b;
        if (gb == 0) {   // l_aux from totals (b = cnt_tot, mt = me_tot)
            float v = (mt / (float)NTOK) * ((float)b / (float)NTOK);
            #pragma unroll
            for (int off = 32; off > 0; off >>= 1) v += __shfl_xor(v, off);
            if (tid == 0) out[0] = v * (float)NEXP;
        }
    }
    __syncthreads();

    // ---- scatter this tile's 32 tokens straight from LDS ----------------
    if (tid < 32) {
        int e   = exp_s[tid];
        int loc = bo_s[e] + rk_s[tid];
        if (loc < CAP) {
            int p = 1 + (tok0 + tid) * (NEXP * CAP) + e * CAP + loc;
            out[(size_t)p]      = gt_s[tid];   // combine
            out[(size_t)p + RF] = 1.0f;        // dispatch
        }
    }
}

extern "C" void kernel_launch(void* const* d_in, const int* in_sizes, int n_in,
                              void* d_out, int out_size, void* d_ws, size_t ws_size,
                              hipStream_t stream)
{
    const float* x  = (const float*)d_in[0];
    const float* wg = (const float*)d_in[1];
    float* out = (float*)d_out;

    char* ws = (char*)d_ws;
    int*   counts_g = (int*)  (ws);             // 64 KB
    float* me_g     = (float*)(ws + 65536);     // 64 KB
    int*   flags    = (int*)  (ws + 131072);    // 1 KB  (total 129 KB + 1 KB)

    // flags must start at 0 every graph replay (ws is poisoned): a
    // capturable memset node, ~1 KB.
    hipMemsetAsync(flags, 0, NTILE * sizeof(int), stream);

    moe_one<<<NTILE, 512, 0, stream>>>(x, wg, out, counts_g, me_g, flags);
}

// Round 6
// 592.790 us; speedup vs baseline: 1.1383x; 1.0261x over previous
//
#include <hip/hip_runtime.h>
#include <math.h>

#define DIM     2048
#define NEXP    64
#define CAP     128
#define NTOK    8192
#define NTILE   256            // 256 tiles of 32 tokens
#define KC      256            // K-chunk staged in LDS
#define NCH     (DIM/KC)       // 8 chunks
#define XWSTR   260            // row stride for xs/ws tiles (KC+4)
#define PSTR    68             // row stride for partial/logit tiles
#define RF      67108864       // floats per output region (S*E*C)

typedef float vfloat4 __attribute__((ext_vector_type(4)));

// ---- 1. gate GEMM + interleaved zero-fill + softmax/argmax/rank ----
// Best-measured config (591.2 / 594.5 us on identical code). The 537 MB
// zero-fill is folded into the GEMM's K-loop: 32 NT f4 stores per thread
// per chunk, issued AFTER the staging loads (vmcnt retires in order ->
// ds_write waits only on the older load). The per-chunk barrier drain of
// the stores IS the HBM write wall; the GEMM hides inside it instead of
// running serially after it. Six structural alternatives (split fill,
// raw-barrier overlap, cooperative, decoupled lookback) all measured
// equal or worse (594-675); see session journal R0-R5.
__global__ __launch_bounds__(512, 2) void gate_fill(
    const float* __restrict__ x, const float* __restrict__ wg,
    float* __restrict__ out,
    int* __restrict__ expert_idx, float* __restrict__ gate_top,
    int* __restrict__ rank,
    float* __restrict__ me_partial, int* __restrict__ counts)
{
    __shared__ __align__(16) float smem[(32 + NEXP) * XWSTR]; // 99,840 B
    __shared__ float me_w[8 * NEXP];
    __shared__ int   cnt_w[8 * NEXP];
    __shared__ int   exp_s[32];

    float* xs = smem;                 // [32][XWSTR]
    float* ws = smem + 32 * XWSTR;    // [64][XWSTR]

    const int tid  = threadIdx.x;
    const int gb   = blockIdx.x;
    const int tok0 = gb * 32;
    const int sl   = tid >> 5;        // k-slice 0..15
    const int i    = tid & 31;
    const int tg   = i & 3;           // token group
    const int eg   = i >> 2;          // expert group 0..7
    const int kb   = sl * 16;         // slice's kk base within chunk

    vfloat4* o4 = reinterpret_cast<vfloat4*>(out);
    const vfloat4 z4 = {0.f, 0.f, 0.f, 0.f};

    if (gb == 0 && tid == 0)
        out[134217728ull] = 0.0f;     // the one float past the f4 span

    float acc[8][8] = {};

    for (int ch = 0; ch < NCH; ++ch) {
        const int k0 = ch * KC;
        // staging loads FIRST (critical path)...
        #pragma unroll
        for (int q = 0; q < 4; ++q) {
            int id = tid + (q << 9);
            int r = id >> 6, c = id & 63;
            float4 v = *(const float4*)(x + (size_t)(tok0 + r) * DIM + k0 + 4 * c);
            *(float4*)(&xs[r * XWSTR + 4 * c]) = v;
        }
        #pragma unroll
        for (int q = 0; q < 8; ++q) {
            int id = tid + (q << 9);
            int r = id >> 6, c = id & 63;
            float4 v = *(const float4*)(wg + (size_t)r * DIM + k0 + 4 * c);
            *(float4*)(&ws[r * XWSTR + 4 * c]) = v;
        }
        // ...then this chunk's slice of the zero-fill (independent stores;
        // they drain during/after the inner loop, at the barrier).
        {
            size_t base = (size_t)gb * 131072 + (size_t)(ch << 14) + tid;
            #pragma unroll
            for (int q = 0; q < 32; ++q)
                __builtin_nontemporal_store(z4, &o4[base + (size_t)(q << 9)]);
        }
        __syncthreads();

        #pragma unroll
        for (int q2 = 0; q2 < 4; ++q2) {
            const int kk = kb + 4 * q2;
            float4 xt[8], we[8];
            #pragma unroll
            for (int j = 0; j < 8; ++j)
                xt[j] = *(const float4*)(&xs[(tg + 4 * j) * XWSTR + kk]);
            #pragma unroll
            for (int m = 0; m < 8; ++m)
                we[m] = *(const float4*)(&ws[(eg + 8 * m) * XWSTR + kk]);
            #pragma unroll
            for (int j = 0; j < 8; ++j)
                #pragma unroll
                for (int m = 0; m < 8; ++m) {
                    acc[j][m] = fmaf(xt[j].x, we[m].x, acc[j][m]);
                    acc[j][m] = fmaf(xt[j].y, we[m].y, acc[j][m]);
                    acc[j][m] = fmaf(xt[j].z, we[m].z, acc[j][m]);
                    acc[j][m] = fmaf(xt[j].w, we[m].w, acc[j][m]);
                }
        }
        __syncthreads();
    }

    // ---- reduce 16 k-slices through LDS ----
    float* part = smem;                 // [8][32][PSTR]
    float* lgt  = smem + 8 * 32 * PSTR; // [32][PSTR]
    if (sl >= 8) {
        #pragma unroll
        for (int j = 0; j < 8; ++j)
            #pragma unroll
            for (int m = 0; m < 8; ++m)
                part[((sl - 8) * 32 + tg + 4 * j) * PSTR + eg + 8 * m] = acc[j][m];
    }
    __syncthreads();
    if (sl < 8) {
        #pragma unroll
        for (int j = 0; j < 8; ++j)
            #pragma unroll
            for (int m = 0; m < 8; ++m) {
                int idx = (sl * 32 + tg + 4 * j) * PSTR + eg + 8 * m;
                part[idx] += acc[j][m];
            }
    }
    __syncthreads();

    {
        int t  = tid >> 4;
        int e0 = (tid & 15) << 2;
        float4 a = {0, 0, 0, 0};
        #pragma unroll
        for (int s2 = 0; s2 < 8; ++s2) {
            float4 p = *(const float4*)(&part[(s2 * 32 + t) * PSTR + e0]);
            a.x += p.x; a.y += p.y; a.z += p.z; a.w += p.w;
        }
        *(float4*)(&lgt[t * PSTR + e0]) = a;
    }
    __syncthreads();

    // ---- softmax + argmax: 8 waves x 4 rows, lane = expert ----
    const int lane = tid & 63;
    const int wv   = tid >> 6;
    float me_acc  = 0.0f;
    int   cnt_acc = 0;
    #pragma unroll
    for (int r4 = 0; r4 < 4; ++r4) {
        int row = wv * 4 + r4;
        float v = lgt[row * PSTR + lane];
        float m = v; int mi = lane;
        #pragma unroll
        for (int off = 32; off > 0; off >>= 1) {
            float om  = __shfl_xor(m, off);
            int   omi = __shfl_xor(mi, off);
            if (om > m || (om == m && omi < mi)) { m = om; mi = omi; }
        }
        float ex = __expf(v - m);
        float sm = ex;
        #pragma unroll
        for (int off = 32; off > 0; off >>= 1) sm += __shfl_xor(sm, off);
        me_acc += ex / sm;
        if (lane == mi) {
            expert_idx[tok0 + row] = mi;
            gate_top[tok0 + row]   = 1.0f / sm;
            exp_s[row] = mi;
            ++cnt_acc;
        }
    }
    me_w[wv * NEXP + lane]  = me_acc;
    cnt_w[wv * NEXP + lane] = cnt_acc;
    __syncthreads();

    if (tid < 32) {   // within-tile rank (token order)
        int e = exp_s[tid];
        int rk = 0;
        for (int u = 0; u < tid; ++u) rk += (exp_s[u] == e) ? 1 : 0;
        rank[tok0 + tid] = rk;
    }
    if (tid < NEXP) {
        float ms = 0.f; int cs = 0;
        #pragma unroll
        for (int w = 0; w < 8; ++w) { ms += me_w[w * NEXP + tid]; cs += cnt_w[w * NEXP + tid]; }
        me_partial[gb * NEXP + tid] = ms;
        counts[gb * NEXP + tid]     = cs;
    }
}

// ---- 2. prefix + l_aux + direct scatter (unchanged, verified) ----
__global__ __launch_bounds__(1024) void prefix_laux(
    const float* __restrict__ me_partial, const int* __restrict__ counts,
    const int* __restrict__ expert_idx, const int* __restrict__ rank,
    const float* __restrict__ gate_top, float* __restrict__ out)
{
    __shared__ int   bo_l[NTILE * NEXP];   // 64 KB exclusive offsets
    __shared__ int   cnt_l[16 * NEXP];
    __shared__ float me_l[16 * NEXP];
    __shared__ int   cnt_tot[NEXP];
    __shared__ float me_tot[NEXP];

    const int tid = threadIdx.x;
    const int e   = tid & 63;
    const int g   = tid >> 6;          // 0..15

    int cs = 0; float ms = 0.f;
    #pragma unroll
    for (int i = 0; i < 16; ++i) {
        int t = g * 16 + i;
        cs += counts[t * NEXP + e];
        ms += me_partial[t * NEXP + e];
    }
    cnt_l[g * NEXP + e] = cs;
    me_l[g * NEXP + e]  = ms;
    __syncthreads();

    if (g == 0) {
        int run = 0; float mt = 0.f;
        #pragma unroll
        for (int i = 0; i < 16; ++i) {
            int c = cnt_l[i * NEXP + e];
            cnt_l[i * NEXP + e] = run;
            run += c;
            mt  += me_l[i * NEXP + e];
        }
        cnt_tot[e] = run;
        me_tot[e]  = mt;
    }
    __syncthreads();

    int run = cnt_l[g * NEXP + e];
    #pragma unroll
    for (int i = 0; i < 16; ++i) {
        int t = g * 16 + i;
        bo_l[t * NEXP + e] = run;
        run += counts[t * NEXP + e];
    }
    __syncthreads();

    if (tid < NEXP) {
        float v = (me_tot[e] / (float)NTOK) * ((float)cnt_tot[e] / (float)NTOK);
        #pragma unroll
        for (int off = 32; off > 0; off >>= 1) v += __shfl_xor(v, off);
        if (e == 0) out[0] = v * (float)NEXP;   // mean(me*ce)*E*E == sum*E
    }

    #pragma unroll
    for (int ii = 0; ii < 8; ++ii) {           // direct scatter of nonzeros
        int s  = tid + (ii << 10);
        int ex = expert_idx[s];
        int loc = bo_l[(s >> 5) * NEXP + ex] + rank[s];
        if (loc < CAP) {
            size_t off = 1 + (size_t)s * (NEXP * CAP) + (size_t)ex * CAP + loc;
            out[off]              = gate_top[s];   // combine
            out[off + (size_t)RF] = 1.0f;          // dispatch
        }
    }
}

extern "C" void kernel_launch(void* const* d_in, const int* in_sizes, int n_in,
                              void* d_out, int out_size, void* d_ws, size_t ws_size,
                              hipStream_t stream)
{
    const float* x  = (const float*)d_in[0];
    const float* wg = (const float*)d_in[1];
    float* out = (float*)d_out;

    char* ws = (char*)d_ws;
    int*   expert_idx = (int*)  (ws);             // 32 KB
    float* gate_top   = (float*)(ws + 32768);     // 32 KB
    int*   rank       = (int*)  (ws + 65536);     // 32 KB
    float* me_partial = (float*)(ws + 98304);     // 64 KB
    int*   counts     = (int*)  (ws + 163840);    // 64 KB  (total 224 KB)

    gate_fill<<<NTILE, 512, 0, stream>>>(x, wg, out, expert_idx, gate_top,
                                         rank, me_partial, counts);
    prefix_laux<<<1, 1024, 0, stream>>>(me_partial, counts, expert_idx, rank,
                                        gate_top, out);
}